// Round 6
// baseline (129.102 us; speedup 1.0000x reference)
//
#include <hip/hip_runtime.h>

#define Bb 4
#define Qn 256
#define Kn 1024
#define Hn 128

// Projections pre-scaled by 2*log2(e) and exponentiated: Eq=2^(s*qp), Ek=2^(s*kp)
// => e^{2(qp+kp)} = Eq*Ek, and tanh(qp+kp) = 1 - 2/(1+Eq*Ek).
constexpr float SCALE = 2.88539008177792681f;  // 2*log2(e)

#if __has_builtin(__builtin_amdgcn_exp2f)
#define EXP2F(x) __builtin_amdgcn_exp2f(x)
#else
#define EXP2F(x) exp2f(x)
#endif
#if __has_builtin(__builtin_amdgcn_rcpf)
#define RCPF(x) __builtin_amdgcn_rcpf(x)
#else
#define RCPF(x) (1.0f / (x))
#endif

// ---------------------------------------------------------------------------
// K1: fused projections. Blocks [0, Bb*Qn/4): query -> Eq (row-major).
// Blocks [Bb*Qn/4, +Bb*Kn/4): key -> EkT (transposed [b,h,k]).
// Both stored as exp2(SCALE * proj).
// ---------------------------------------------------------------------------
__global__ __launch_bounds__(128) void proj_kernel(const float* __restrict__ query,
                                                   const float* __restrict__ key,
                                                   const float* __restrict__ Wq,
                                                   const float* __restrict__ Wk,
                                                   float* __restrict__ eq,
                                                   float* __restrict__ ekT) {
    __shared__ float4 xs[128];  // 4 rows x 32 float4
    const int tid = threadIdx.x;
    const bool isQ = blockIdx.x < (Bb * Qn / 4);
    const int r0 = (isQ ? blockIdx.x : blockIdx.x - Bb * Qn / 4) * 4;
    const float* x = isQ ? query : key;
    const float* W = isQ ? Wq : Wk;

    xs[tid] = ((const float4*)(x + (size_t)r0 * Hn))[tid];
    __syncthreads();
    const float4* W4 = (const float4*)W + (size_t)tid * (Hn / 4);
    float acc0 = 0.f, acc1 = 0.f, acc2 = 0.f, acc3 = 0.f;
#pragma unroll 8
    for (int d = 0; d < Hn / 4; ++d) {
        float4 w = W4[d];
        float4 a0 = xs[d];
        float4 a1 = xs[32 + d];
        float4 a2 = xs[64 + d];
        float4 a3 = xs[96 + d];
        acc0 = fmaf(w.x, a0.x, fmaf(w.y, a0.y, fmaf(w.z, a0.z, fmaf(w.w, a0.w, acc0))));
        acc1 = fmaf(w.x, a1.x, fmaf(w.y, a1.y, fmaf(w.z, a1.z, fmaf(w.w, a1.w, acc1))));
        acc2 = fmaf(w.x, a2.x, fmaf(w.y, a2.y, fmaf(w.z, a2.z, fmaf(w.w, a2.w, acc2))));
        acc3 = fmaf(w.x, a3.x, fmaf(w.y, a3.y, fmaf(w.z, a3.z, fmaf(w.w, a3.w, acc3))));
    }
    if (isQ) {
        eq[(size_t)(r0 + 0) * Hn + tid] = EXP2F(acc0 * SCALE);
        eq[(size_t)(r0 + 1) * Hn + tid] = EXP2F(acc1 * SCALE);
        eq[(size_t)(r0 + 2) * Hn + tid] = EXP2F(acc2 * SCALE);
        eq[(size_t)(r0 + 3) * Hn + tid] = EXP2F(acc3 * SCALE);
    } else {
        const int b = r0 / Kn;
        const int k0 = r0 % Kn;
        float4 res = make_float4(EXP2F(acc0 * SCALE), EXP2F(acc1 * SCALE),
                                 EXP2F(acc2 * SCALE), EXP2F(acc3 * SCALE));
        ((float4*)ekT)[(size_t)(b * Hn + tid) * (Kn / 4) + (k0 >> 2)] = res;
    }
}

// ---------------------------------------------------------------------------
// K2: fused score + softmax + context. Block = 1024 thr (16 waves), (b, 2 q).
// Grid = 512 blocks -> 8192 waves = 32 waves/CU (vs 16 in prior round).
//   A: a[q][k] = sum_h v[h] * rcp(fma(Eq,Ek,1))  (thread = (qq, 2 k), float2)
//   B: softmax via min-reduce of a (8 waves per q-row, shfl + LDS)
//   C: ctx[q][h] = sum_k w[q][k]*value[b,k,h], k split 4 ways + LDS reduce
// mask skipped: -1e-9*(1-mask) perturbs weights by ~1e-12.
// ---------------------------------------------------------------------------
__global__ __launch_bounds__(1024) void fused_attn_kernel(const float* __restrict__ eq,
                                                          const float* __restrict__ ekT,
                                                          const float* __restrict__ v,
                                                          const float* __restrict__ value,
                                                          float* __restrict__ attn,
                                                          float* __restrict__ ctx) {
    const int tid = threadIdx.x;
    const int q0 = blockIdx.x * 2;
    const int b = blockIdx.y;

    __shared__ __align__(16) float2 qs[Hn][2];  // [h][qq] = {Eq, v[h]}
    __shared__ __align__(16) float sc[2][Kn];   // weights
    __shared__ float red[32];                   // [0..15] min/wave, [16..31] sum
    __shared__ float pl[4][2][Hn];              // ctx partials [kq][q][h]

    if (tid < Hn) {
        float e0 = eq[((size_t)b * Qn + q0) * Hn + tid];
        float e1 = eq[((size_t)b * Qn + q0 + 1) * Hn + tid];
        float vh = v[tid];
        qs[tid][0] = make_float2(e0, vh);
        qs[tid][1] = make_float2(e1, vh);
    }
    __syncthreads();

    // ---- phase A: scores (thread = (qq = tid>>9, t = tid&511 -> k=2t,2t+1))
    const int qq = tid >> 9;
    const int t = tid & 511;
    const float2* kp2 = (const float2*)(ekT + (size_t)b * Hn * Kn) + t;
    float a0 = 0.f, a1 = 0.f;
#pragma unroll 8
    for (int h = 0; h < Hn; ++h) {
        float2 kv = kp2[(size_t)h * (Kn / 2)];
        float2 qv = qs[h][qq];  // {Eq, vh}
        float r;
        r = RCPF(fmaf(qv.x, kv.x, 1.0f)); a0 = fmaf(qv.y, r, a0);
        r = RCPF(fmaf(qv.x, kv.y, 1.0f)); a1 = fmaf(qv.y, r, a1);
    }

    // ---- phase B: softmax. score = V - 2a -> shift-invariant: min-reduce a.
    const int lane = tid & 63, wv = tid >> 6;  // wv 0..15; waves [qq*8, qq*8+8)
    float mn = fminf(a0, a1);
#pragma unroll
    for (int off = 32; off; off >>= 1) mn = fminf(mn, __shfl_xor(mn, off));
    if (lane == 0) red[wv] = mn;
    __syncthreads();
    {
        const float* rq = &red[qq * 8];
        mn = fminf(fminf(fminf(rq[0], rq[1]), fminf(rq[2], rq[3])),
                   fminf(fminf(rq[4], rq[5]), fminf(rq[6], rq[7])));
    }

    float e0 = EXP2F((mn - a0) * SCALE);
    float e1 = EXP2F((mn - a1) * SCALE);
    float s = e0 + e1;
#pragma unroll
    for (int off = 32; off; off >>= 1) s += __shfl_xor(s, off);
    if (lane == 0) red[16 + wv] = s;
    __syncthreads();
    {
        const float* rq = &red[16 + qq * 8];
        s = ((rq[0] + rq[1]) + (rq[2] + rq[3])) + ((rq[4] + rq[5]) + (rq[6] + rq[7]));
    }
    const float inv = RCPF(s);

    float2 w2 = make_float2(e0 * inv, e1 * inv);
    ((float2*)&sc[qq][0])[t] = w2;
    ((float2*)(attn + ((size_t)b * Qn + q0 + qq) * Kn))[t] = w2;
    __syncthreads();

    // ---- phase C: context (thread = (kq = tid>>8, q2 = (tid>>7)&1, hq)) ----
    const int hq = tid & 127;
    const int q2 = (tid >> 7) & 1;
    const int kq = tid >> 8;  // 0..3, k in [kq*256, kq*256+256)
    const float* vb = value + ((size_t)b * Kn + kq * (Kn / 4)) * Hn + hq;
    const float4* wrow = (const float4*)&sc[q2][kq * (Kn / 4)];
    float acc = 0.f;
#pragma unroll 4
    for (int k4 = 0; k4 < Kn / 16; ++k4) {
        float4 wv4 = wrow[k4];
        acc = fmaf(wv4.x, vb[(size_t)(4 * k4 + 0) * Hn], acc);
        acc = fmaf(wv4.y, vb[(size_t)(4 * k4 + 1) * Hn], acc);
        acc = fmaf(wv4.z, vb[(size_t)(4 * k4 + 2) * Hn], acc);
        acc = fmaf(wv4.w, vb[(size_t)(4 * k4 + 3) * Hn], acc);
    }
    pl[kq][q2][hq] = acc;
    __syncthreads();
    if (tid < 256) {
        const int qo = tid >> 7, ho = tid & 127;
        ctx[((size_t)b * Qn + q0 + qo) * Hn + ho] =
            (pl[0][qo][ho] + pl[1][qo][ho]) + (pl[2][qo][ho] + pl[3][qo][ho]);
    }
}

// ---------------------------------------------------------------------------
extern "C" void kernel_launch(void* const* d_in, const int* in_sizes, int n_in,
                              void* d_out, int out_size, void* d_ws, size_t ws_size,
                              hipStream_t stream) {
    const float* query = (const float*)d_in[0];  // (4,256,128)
    const float* key = (const float*)d_in[1];    // (4,1024,128)
    const float* value = (const float*)d_in[2];  // (4,1024,128)
    // d_in[3] = mask: unused (NEG_MASK_SCALE = -1e-9 -> effect ~1e-12)
    const float* Wq = (const float*)d_in[4];
    const float* Wk = (const float*)d_in[5];
    const float* v = (const float*)d_in[6];

    float* out = (float*)d_out;
    float* attn = out;                        // B*Q*K floats
    float* ctx = out + (size_t)Bb * Qn * Kn;  // B*Q*H floats

    float* ws = (float*)d_ws;
    float* eq = ws;             // 131072 floats: exp2(SCALE*qp)
    float* ekT = ws + 131072;   // 524288 floats: exp2(SCALE*kp), [b,h,k]

    proj_kernel<<<dim3(Bb * Qn / 4 + Bb * Kn / 4), dim3(128), 0, stream>>>(
        query, key, Wq, Wk, eq, ekT);
    fused_attn_kernel<<<dim3(Qn / 2, Bb), dim3(1024), 0, stream>>>(
        eq, ekT, v, value, attn, ctx);
}

// Round 7
// 117.665 us; speedup vs baseline: 1.0972x; 1.0972x over previous
//
#include <hip/hip_runtime.h>

#define Bb 4
#define Qn 256
#define Kn 1024
#define Hn 128
#define QT 4  // q-rows per fused block

// Projections pre-scaled by 2*log2(e) and exponentiated: Eq=2^(s*qp), Ek=2^(s*kp)
// => e^{2(qp+kp)} = Eq*Ek, and tanh(qp+kp) = 1 - 2/(1+Eq*Ek).
constexpr float SCALE = 2.88539008177792681f;  // 2*log2(e)

#if __has_builtin(__builtin_amdgcn_exp2f)
#define EXP2F(x) __builtin_amdgcn_exp2f(x)
#else
#define EXP2F(x) exp2f(x)
#endif
#if __has_builtin(__builtin_amdgcn_rcpf)
#define RCPF(x) __builtin_amdgcn_rcpf(x)
#else
#define RCPF(x) (1.0f / (x))
#endif

// ---------------------------------------------------------------------------
// K1: fused projections. Blocks [0, Bb*Qn/4): query -> Eq (row-major).
// Blocks [Bb*Qn/4, +Bb*Kn/4): key -> EkT (transposed [b,h,k]).
// Both stored as exp2(SCALE * proj).
// ---------------------------------------------------------------------------
__global__ __launch_bounds__(128) void proj_kernel(const float* __restrict__ query,
                                                   const float* __restrict__ key,
                                                   const float* __restrict__ Wq,
                                                   const float* __restrict__ Wk,
                                                   float* __restrict__ eq,
                                                   float* __restrict__ ekT) {
    __shared__ float4 xs[128];  // 4 rows x 32 float4
    const int tid = threadIdx.x;
    const bool isQ = blockIdx.x < (Bb * Qn / 4);
    const int r0 = (isQ ? blockIdx.x : blockIdx.x - Bb * Qn / 4) * 4;
    const float* x = isQ ? query : key;
    const float* W = isQ ? Wq : Wk;

    xs[tid] = ((const float4*)(x + (size_t)r0 * Hn))[tid];
    __syncthreads();
    const float4* W4 = (const float4*)W + (size_t)tid * (Hn / 4);
    float acc0 = 0.f, acc1 = 0.f, acc2 = 0.f, acc3 = 0.f;
#pragma unroll 8
    for (int d = 0; d < Hn / 4; ++d) {
        float4 w = W4[d];
        float4 a0 = xs[d];
        float4 a1 = xs[32 + d];
        float4 a2 = xs[64 + d];
        float4 a3 = xs[96 + d];
        acc0 = fmaf(w.x, a0.x, fmaf(w.y, a0.y, fmaf(w.z, a0.z, fmaf(w.w, a0.w, acc0))));
        acc1 = fmaf(w.x, a1.x, fmaf(w.y, a1.y, fmaf(w.z, a1.z, fmaf(w.w, a1.w, acc1))));
        acc2 = fmaf(w.x, a2.x, fmaf(w.y, a2.y, fmaf(w.z, a2.z, fmaf(w.w, a2.w, acc2))));
        acc3 = fmaf(w.x, a3.x, fmaf(w.y, a3.y, fmaf(w.z, a3.z, fmaf(w.w, a3.w, acc3))));
    }
    if (isQ) {
        eq[(size_t)(r0 + 0) * Hn + tid] = EXP2F(acc0 * SCALE);
        eq[(size_t)(r0 + 1) * Hn + tid] = EXP2F(acc1 * SCALE);
        eq[(size_t)(r0 + 2) * Hn + tid] = EXP2F(acc2 * SCALE);
        eq[(size_t)(r0 + 3) * Hn + tid] = EXP2F(acc3 * SCALE);
    } else {
        const int b = r0 / Kn;
        const int k0 = r0 % Kn;
        float4 res = make_float4(EXP2F(acc0 * SCALE), EXP2F(acc1 * SCALE),
                                 EXP2F(acc2 * SCALE), EXP2F(acc3 * SCALE));
        ((float4*)ekT)[(size_t)(b * Hn + tid) * (Kn / 4) + (k0 >> 2)] = res;
    }
}

// ---------------------------------------------------------------------------
// K2: fused score + softmax + context. Block = 1024 thr, (b, QT=4 q-rows).
// Grid = (Qn/QT=64, Bb=4) = 256 blocks = 1 per CU. Key change vs R6: each
// block covers 4 q-rows with thread=k, so the 512 KB ekT b-slice is read
// ONCE per block with no intra-block duplication -> 4x less L2 traffic.
//   A: thread k: a[q] = sum_h v[h]*rcp(fma(Eq[q][h],Ek[h][k],1)), 4 q-chains
//   B: softmax via min-reduce of a (shift-invariant; V-term dropped)
//   C: ctx: thread=(kc 0..7, q, h4): float4 over h, split-k 8, LDS reduce
// mask skipped: -1e-9*(1-mask) perturbs weights by ~1e-12.
// ---------------------------------------------------------------------------
__global__ __launch_bounds__(1024) void fused_attn_kernel(const float* __restrict__ eq,
                                                          const float* __restrict__ ekT,
                                                          const float* __restrict__ v,
                                                          const float* __restrict__ value,
                                                          float* __restrict__ attn,
                                                          float* __restrict__ ctx) {
    const int tid = threadIdx.x;
    const int q0 = blockIdx.x * QT;
    const int b = blockIdx.y;

    __shared__ __align__(16) float4 qs4[Hn];      // {Eq[q0..q0+3][h]}
    __shared__ float vs[Hn];                      // v[h]
    __shared__ __align__(16) float sc[QT][Kn];    // weights (16 KB)
    __shared__ float red[16][QT];                 // per-wave partials
    __shared__ __align__(16) float4 pl[8][QT][Hn / 4];  // ctx partials (16 KB)

    if (tid < Hn) vs[tid] = v[tid];
    if (tid < QT * Hn) {
        const int q = tid >> 7, h = tid & 127;
        ((float*)&qs4[h])[q] = eq[((size_t)b * Qn + q0 + q) * Hn + h];
    }
    __syncthreads();

    // ---- phase A: thread = k, 4 q-chains ----
    const int k = tid;
    const float* ek = ekT + (size_t)b * Hn * Kn + k;
    float a0 = 0.f, a1 = 0.f, a2 = 0.f, a3 = 0.f;
#pragma unroll 8
    for (int h = 0; h < Hn; ++h) {
        const float kv = ek[(size_t)h * Kn];
        const float4 qv = qs4[h];
        const float vh = vs[h];
        float r;
        r = RCPF(fmaf(qv.x, kv, 1.0f)); a0 = fmaf(vh, r, a0);
        r = RCPF(fmaf(qv.y, kv, 1.0f)); a1 = fmaf(vh, r, a1);
        r = RCPF(fmaf(qv.z, kv, 1.0f)); a2 = fmaf(vh, r, a2);
        r = RCPF(fmaf(qv.w, kv, 1.0f)); a3 = fmaf(vh, r, a3);
    }

    // ---- phase B: softmax (score = V - 2a, shift-invariant -> min-reduce a)
    const int lane = tid & 63, wv = tid >> 6;  // 16 waves
    float m0 = a0, m1 = a1, m2 = a2, m3 = a3;
#pragma unroll
    for (int off = 32; off; off >>= 1) {
        m0 = fminf(m0, __shfl_xor(m0, off));
        m1 = fminf(m1, __shfl_xor(m1, off));
        m2 = fminf(m2, __shfl_xor(m2, off));
        m3 = fminf(m3, __shfl_xor(m3, off));
    }
    if (lane == 0) {
        red[wv][0] = m0; red[wv][1] = m1; red[wv][2] = m2; red[wv][3] = m3;
    }
    __syncthreads();
    m0 = red[0][0]; m1 = red[0][1]; m2 = red[0][2]; m3 = red[0][3];
#pragma unroll
    for (int w = 1; w < 16; ++w) {
        m0 = fminf(m0, red[w][0]); m1 = fminf(m1, red[w][1]);
        m2 = fminf(m2, red[w][2]); m3 = fminf(m3, red[w][3]);
    }
    __syncthreads();  // red reused for sums

    float e0 = EXP2F((m0 - a0) * SCALE);
    float e1 = EXP2F((m1 - a1) * SCALE);
    float e2 = EXP2F((m2 - a2) * SCALE);
    float e3 = EXP2F((m3 - a3) * SCALE);
    float s0 = e0, s1 = e1, s2 = e2, s3 = e3;
#pragma unroll
    for (int off = 32; off; off >>= 1) {
        s0 += __shfl_xor(s0, off);
        s1 += __shfl_xor(s1, off);
        s2 += __shfl_xor(s2, off);
        s3 += __shfl_xor(s3, off);
    }
    if (lane == 0) {
        red[wv][0] = s0; red[wv][1] = s1; red[wv][2] = s2; red[wv][3] = s3;
    }
    __syncthreads();
    s0 = red[0][0]; s1 = red[0][1]; s2 = red[0][2]; s3 = red[0][3];
#pragma unroll
    for (int w = 1; w < 16; ++w) {
        s0 += red[w][0]; s1 += red[w][1]; s2 += red[w][2]; s3 += red[w][3];
    }

    const float w0 = e0 * RCPF(s0);
    const float w1 = e1 * RCPF(s1);
    const float w2 = e2 * RCPF(s2);
    const float w3 = e3 * RCPF(s3);
    sc[0][k] = w0; sc[1][k] = w1; sc[2][k] = w2; sc[3][k] = w3;
    float* arow = attn + ((size_t)b * Qn + q0) * Kn + k;
    arow[0 * Kn] = w0; arow[1 * Kn] = w1; arow[2 * Kn] = w2; arow[3 * Kn] = w3;
    __syncthreads();

    // ---- phase C: context. thread = (kc = tid>>7, q = (tid>>5)&3, h4 = tid&31)
    const int kc = tid >> 7;          // 0..7: k in [kc*128, +128)
    const int cq = (tid >> 5) & 3;    // q row
    const int h4 = tid & 31;          // float4 index over h
    const float4* vb = (const float4*)(value + ((size_t)b * Kn + kc * 128) * Hn) + h4;
    const float* wr = &sc[cq][kc * 128];
    float4 acc = make_float4(0.f, 0.f, 0.f, 0.f);
#pragma unroll 4
    for (int kk = 0; kk < 128; ++kk) {
        const float wgt = wr[kk];
        const float4 vv = vb[(size_t)kk * (Hn / 4)];
        acc.x = fmaf(wgt, vv.x, acc.x);
        acc.y = fmaf(wgt, vv.y, acc.y);
        acc.z = fmaf(wgt, vv.z, acc.z);
        acc.w = fmaf(wgt, vv.w, acc.w);
    }
    pl[kc][cq][h4] = acc;
    __syncthreads();
    if (tid < QT * Hn / 4) {  // 128 threads
        const int q = tid >> 5, h = tid & 31;
        float4 r0 = pl[0][q][h], r1 = pl[1][q][h], r2 = pl[2][q][h], r3 = pl[3][q][h];
        float4 r4 = pl[4][q][h], r5 = pl[5][q][h], r6 = pl[6][q][h], r7 = pl[7][q][h];
        float4 sum;
        sum.x = ((r0.x + r1.x) + (r2.x + r3.x)) + ((r4.x + r5.x) + (r6.x + r7.x));
        sum.y = ((r0.y + r1.y) + (r2.y + r3.y)) + ((r4.y + r5.y) + (r6.y + r7.y));
        sum.z = ((r0.z + r1.z) + (r2.z + r3.z)) + ((r4.z + r5.z) + (r6.z + r7.z));
        sum.w = ((r0.w + r1.w) + (r2.w + r3.w)) + ((r4.w + r5.w) + (r6.w + r7.w));
        ((float4*)(ctx + ((size_t)b * Qn + q0 + q) * Hn))[h] = sum;
    }
}

// ---------------------------------------------------------------------------
extern "C" void kernel_launch(void* const* d_in, const int* in_sizes, int n_in,
                              void* d_out, int out_size, void* d_ws, size_t ws_size,
                              hipStream_t stream) {
    const float* query = (const float*)d_in[0];  // (4,256,128)
    const float* key = (const float*)d_in[1];    // (4,1024,128)
    const float* value = (const float*)d_in[2];  // (4,1024,128)
    // d_in[3] = mask: unused (NEG_MASK_SCALE = -1e-9 -> effect ~1e-12)
    const float* Wq = (const float*)d_in[4];
    const float* Wk = (const float*)d_in[5];
    const float* v = (const float*)d_in[6];

    float* out = (float*)d_out;
    float* attn = out;                        // B*Q*K floats
    float* ctx = out + (size_t)Bb * Qn * Kn;  // B*Q*H floats

    float* ws = (float*)d_ws;
    float* eq = ws;             // 131072 floats: exp2(SCALE*qp)
    float* ekT = ws + 131072;   // 524288 floats: exp2(SCALE*kp), [b,h,k]

    proj_kernel<<<dim3(Bb * Qn / 4 + Bb * Kn / 4), dim3(128), 0, stream>>>(
        query, key, Wq, Wk, eq, ekT);
    fused_attn_kernel<<<dim3(Qn / QT, Bb), dim3(1024), 0, stream>>>(
        eq, ekT, v, value, attn, ctx);
}